// Round 12
// baseline (178.636 us; speedup 1.0000x reference)
//
#include <hip/hip_runtime.h>
#include <cstdint>

#define NB 8192
#define ND 512
#define BM 256
#define BN 256
#define BK 32
#define THREADS 512
#define BUFS 16384      // shorts per buffer (32 KB: A 16KB + B 16KB); 2 buffers = 64 KB

typedef __bf16 bf16x8 __attribute__((ext_vector_type(8)));
typedef float f32x4 __attribute__((ext_vector_type(4)));

__device__ __forceinline__ unsigned short f2bf(float f) {
    union { float f; uint32_t u; } c; c.f = f;
    return (unsigned short)((c.u + 0x7fffu + ((c.u >> 16) & 1u)) >> 16);
}

// async global->LDS, 16B per lane. LDS dest must be wave-uniform; HW adds lane*16.
__device__ __forceinline__ void load16(const void* g, void* l) {
    __builtin_amdgcn_global_load_lds(
        (void __attribute__((address_space(1)))*)(const_cast<void*>(g)),
        (void __attribute__((address_space(3)))*)(l),
        16, 0, 0);
}

// ---------------- kernel 1: L2-normalize rows + cast to bf16 ----------------
__global__ __launch_bounds__(256) void norm_cast(const float* __restrict__ v,
                                                 const float* __restrict__ t,
                                                 unsigned short* __restrict__ vn,
                                                 unsigned short* __restrict__ tn,
                                                 int ns) {
    const int wave = threadIdx.x >> 6;
    const int lane = threadIdx.x & 63;
    const int row = blockIdx.x * 4 + wave;
    const float* src;
    unsigned short* dst;
    if (row < NB) { src = v + (size_t)row * ND; dst = vn + (size_t)row * ns; }
    else { src = t + (size_t)(row - NB) * ND; dst = tn + (size_t)(row - NB) * ns; }
    float4 a = ((const float4*)src)[lane * 2];
    float4 b = ((const float4*)src)[lane * 2 + 1];
    float ss = a.x * a.x + a.y * a.y + a.z * a.z + a.w * a.w
             + b.x * b.x + b.y * b.y + b.z * b.z + b.w * b.w;
#pragma unroll
    for (int off = 32; off; off >>= 1) ss += __shfl_xor(ss, off);
    const float sc = 1.0f / fmaxf(sqrtf(ss), 1e-12f);
    union { unsigned short us[8]; uint4 q; } pk;
    pk.us[0] = f2bf(a.x * sc); pk.us[1] = f2bf(a.y * sc);
    pk.us[2] = f2bf(a.z * sc); pk.us[3] = f2bf(a.w * sc);
    pk.us[4] = f2bf(b.x * sc); pk.us[5] = f2bf(b.y * sc);
    pk.us[6] = f2bf(b.z * sc); pk.us[7] = f2bf(b.w * sc);
    ((uint4*)dst)[lane] = pk.q;
}

// ---------------- kernel 2: cross-tile read-ahead bf16 GEMM + BCE ----------------
// 256x256 tile, BK=32, 8 waves (2Mx4N, wave tile 128x64), 2 LDS buffers (64 KB).
// Register-double-buffered fragments: tile T's frags were ds_read during tile T-1,
// so tile T = pure MFMA (1241 cyc/SIMD) while tile T+1's 12 ds_reads (LDS pipe,
// 1150 cyc/CU) are issued BETWEEN the two MFMA clusters -> LDS hides under MFMA.
// Staging depth 2: STG(T+2) issued at tile T start (its buf region's reads ended
// at T-1), vmcnt(0) at tile end has ~1200 cyc slack vs ~200-500 cyc L2 latency.
// Address math (staging pre-swizzle, read swizzle, epilogue map) identical to R9
// (verified absmax=0, SQ_LDS_BANK_CONFLICT=0).
__global__ __launch_bounds__(THREADS, 1) void gemm_bce(const unsigned short* __restrict__ vn,
                                                       const unsigned short* __restrict__ tn,
                                                       const float* __restrict__ lt,
                                                       const float* __restrict__ bp,
                                                       float* __restrict__ out_sum,
                                                       int ns) {
    __shared__ __align__(16) unsigned short smem[2 * BUFS];  // 64 KB
    __shared__ float red[8];

    const int tid = threadIdx.x;
    const int lane = tid & 63;
    const int wave = tid >> 6;     // 0..7
    const int wr = wave >> 2;      // 0..1
    const int wc = wave & 3;       // 0..3
    const int lq = lane & 15;
    const int lh = lane >> 4;      // 0..3

    const int m0 = (int)(blockIdx.x >> 5) * BM;
    const int n0 = (int)(blockIdx.x & 31) * BN;

    // staging: per wave, A rows [32w..32w+31] + B rows [32w..32w+31], 2 load16 each.
    // lane l -> row +(l>>2), source chunk (l&3)^((l>>3)&3) (pre-swizzled).
    const int schunk = ((lane & 3) ^ ((lane >> 3) & 3)) * 8;
    const unsigned short* sA = vn + (size_t)(m0 + 32 * wave + (lane >> 2)) * ns + schunk;
    const unsigned short* sB = tn + (size_t)(n0 + 32 * wave + (lane >> 2)) * ns + schunk;

#define STG(T, B) do {                                                         \
        unsigned short* _dA = smem + (B) * BUFS + wave * 1024;                 \
        unsigned short* _dB = _dA + 8192;                                      \
        load16(sA + (T) * 32, _dA);                                            \
        load16(sA + (T) * 32 + (size_t)16 * ns, _dA + 512);                    \
        load16(sB + (T) * 32, _dB);                                            \
        load16(sB + (T) * 32 + (size_t)16 * ns, _dB + 512);                    \
    } while (0)

    // reader offsets (shorts): row stride 32; slot = lh ^ ((row>>1)&3).
    const int sl = (lh ^ ((lq >> 1) & 3)) * 8;
    const int aro = (wr * 16 + lq) * 32 + sl;
    const int bro = (wc * 16 + lq) * 32 + sl;
#define RD_A(C, M) (*(const bf16x8*)(smem + (C) * BUFS + aro + (M) * 1024))
#define RD_B(C, N) (*(const bf16x8*)(smem + (C) * BUFS + 8192 + bro + (N) * 2048))

#define BAR __builtin_amdgcn_s_barrier()
#define SCB __builtin_amdgcn_sched_barrier(0)
#define LGK0 asm volatile("s_waitcnt lgkmcnt(0)" ::: "memory")
#define VM0 asm volatile("s_waitcnt vmcnt(0)" ::: "memory")

    f32x4 acc[8][4];
#pragma unroll
    for (int m = 0; m < 8; ++m)
#pragma unroll
        for (int n = 0; n < 4; ++n)
            acc[m][n] = f32x4{0.f, 0.f, 0.f, 0.f};

    // register-double-buffered fragments (all indices compile-time)
    bf16x8 afrX[8], bfrX[4], afrY[8], bfrY[4];

#define RD12(AF, BF, BUF) do {                                                  \
        _Pragma("unroll") for (int mm = 0; mm < 8; ++mm) AF[mm] = RD_A(BUF, mm); \
        _Pragma("unroll") for (int nn = 0; nn < 4; ++nn) BF[nn] = RD_B(BUF, nn); \
    } while (0)

#define MFMAH(AF, BF, MB)                                                       \
    _Pragma("unroll") for (int mm = 0; mm < 4; ++mm)                            \
    _Pragma("unroll") for (int nn = 0; nn < 4; ++nn)                            \
        acc[(MB) + mm][nn] = __builtin_amdgcn_mfma_f32_16x16x32_bf16(           \
            AF[(MB) + mm], BF[nn], acc[(MB) + mm][nn], 0, 0, 0)

    // TILE(T): consume frags AC/BC (read during T-1); read T+1 frags into AN/BN_
    // between MFMA clusters; stage T+2 into buf[T&1] (region dead since T-1).
#define TILE(T, S, R, LAST, AC, BC, AN, BN_) do {                               \
        LGK0; SCB;   /* frags-T in regs; prior reads of buf[T&1] executed */    \
        if (S) STG((T) + 2, (T) & 1);                                           \
        __builtin_amdgcn_s_setprio(1); MFMAH(AC, BC, 0);                        \
        __builtin_amdgcn_s_setprio(0); SCB;                                     \
        if (R) RD12(AN, BN_, ((T) + 1) & 1);                                    \
        SCB;                                                                    \
        __builtin_amdgcn_s_setprio(1); MFMAH(AC, BC, 4);                        \
        __builtin_amdgcn_s_setprio(0); SCB;                                     \
        if (!(LAST)) { VM0; BAR; SCB; }                                         \
    } while (0)

    // prologue: stage tiles 0,1; drain (once); read tile0 frags.
    STG(0, 0);
    STG(1, 1);
    VM0; BAR; SCB;
    RD12(afrX, bfrX, 0);

    TILE(0,  1, 1, 0, afrX, bfrX, afrY, bfrY);
    TILE(1,  1, 1, 0, afrY, bfrY, afrX, bfrX);
    TILE(2,  1, 1, 0, afrX, bfrX, afrY, bfrY);
    TILE(3,  1, 1, 0, afrY, bfrY, afrX, bfrX);
    TILE(4,  1, 1, 0, afrX, bfrX, afrY, bfrY);
    TILE(5,  1, 1, 0, afrY, bfrY, afrX, bfrX);
    TILE(6,  1, 1, 0, afrX, bfrX, afrY, bfrY);
    TILE(7,  1, 1, 0, afrY, bfrY, afrX, bfrX);
    TILE(8,  1, 1, 0, afrX, bfrX, afrY, bfrY);
    TILE(9,  1, 1, 0, afrY, bfrY, afrX, bfrX);
    TILE(10, 1, 1, 0, afrX, bfrX, afrY, bfrY);
    TILE(11, 1, 1, 0, afrY, bfrY, afrX, bfrX);
    TILE(12, 1, 1, 0, afrX, bfrX, afrY, bfrY);
    TILE(13, 1, 1, 0, afrY, bfrY, afrX, bfrX);
    TILE(14, 0, 1, 0, afrX, bfrX, afrY, bfrY);
    TILE(15, 0, 0, 1, afrY, bfrY, afrX, bfrX);

    // epilogue: z = clip(sim/temp + bias); bce = max(z,0) - z*[diag] + log(1+exp(-|z|))
    const float invtemp = __expf(-lt[0]);
    const float bias = bp[0];
    float local = 0.f;
    const int row_base = m0 + wr * 16 + lh * 4;
    const int col_base = n0 + wc * 16 + lq;
#pragma unroll
    for (int m = 0; m < 8; ++m) {
#pragma unroll
        for (int n = 0; n < 4; ++n) {
#pragma unroll
            for (int r = 0; r < 4; ++r) {
                const float s = acc[m][n][r];
                float z = fminf(fmaxf(fmaf(s, invtemp, bias), -30.f), 30.f);
                const int gr = row_base + m * 32 + r;
                const int gc = col_base + n * 64;
                local += fmaxf(z, 0.f) + __logf(1.0f + __expf(-fabsf(z))) - ((gr == gc) ? z : 0.f);
            }
        }
    }
#pragma unroll
    for (int off = 32; off; off >>= 1) local += __shfl_xor(local, off);
    if (lane == 0) red[wave] = local;
    __syncthreads();
    if (tid == 0) {
        float tot = 0.f;
#pragma unroll
        for (int w = 0; w < 8; ++w) tot += red[w];
        atomicAdd(out_sum, tot * (1.0f / 67108864.0f));  // exact 2^-26 mean scale
    }
}

extern "C" void kernel_launch(void* const* d_in, const int* in_sizes, int n_in,
                              void* d_out, int out_size, void* d_ws, size_t ws_size,
                              hipStream_t stream) {
    const float* v = (const float*)d_in[0];
    const float* t = (const float*)d_in[1];
    const float* lt = (const float*)d_in[2];
    const float* bp = (const float*)d_in[3];
    float* out = (float*)d_out;

    const size_t need = (size_t)2 * NB * ND * sizeof(unsigned short);
    unsigned short *vn, *tn;
    int ns;
    if (ws_size >= need) {
        vn = (unsigned short*)d_ws;
        tn = vn + (size_t)NB * ND;
        ns = ND;
    } else {
        vn = (unsigned short*)d_in[0];
        tn = (unsigned short*)d_in[1];
        ns = ND * 2;
    }

    hipMemsetAsync(out, 0, sizeof(float), stream);
    hipLaunchKernelGGL(norm_cast, dim3((2 * NB) / 4), dim3(256), 0, stream, v, t, vn, tn, ns);
    hipLaunchKernelGGL(gemm_bce, dim3((NB / BM) * (NB / BN)), dim3(THREADS), 0, stream,
                       vn, tn, lt, bp, out, ns);
}